// Round 7
// baseline (189.597 us; speedup 1.0000x reference)
//
#include <hip/hip_runtime.h>
#include <stdint.h>

typedef unsigned short u16;
typedef u16  u16x4 __attribute__((ext_vector_type(4)));
typedef u16  u16x8 __attribute__((ext_vector_type(8)));
typedef _Float16 f16x4 __attribute__((ext_vector_type(4)));
typedef _Float16 f16x8 __attribute__((ext_vector_type(8)));
typedef float f32x4 __attribute__((ext_vector_type(4)));
typedef float fvec4 __attribute__((ext_vector_type(4)));

#define B_ 4
#define T_ 2048
#define S_ 2048
#define D_ 512
#define H_ 8
#define HD_ 64
#define M_ 8192   // B*T == B*S
#define K_ 512    // projection inner dim

// workspace offsets in u16 (f16) element units
#define U_QBF  0u          // (free) reused as attn_out
#define U_Q    12582912u   // projected Q f16 (pre-scaled by log2e/8)
#define U_K    16777216u   // projected K f16
#define U_VT   20971520u   // projected V^T f16 (B, D, S) — written by gemm_qkv z=2
#define U_W    25165824u   // Wq,Wk,Wv,Wo f16 (262144 u16 each)
#define U_WSZ  262144u

#define QSCALE 0.1803368801111244f   // log2(e) / sqrt(HD), folded into Q projection

__device__ __forceinline__ u16 f2h(float f) {
    union { _Float16 h; u16 u; } c;
    c.h = (_Float16)f;
    return c.u;
}

// async global->LDS 16B copy: LDS dest = wave-uniform base + lane*16.
// ONLY valid when fragment order is ALSO global-contiguous.
__device__ __forceinline__ void gld16(const u16* g, u16* l) {
    __builtin_amdgcn_global_load_lds(
        (const __attribute__((address_space(1))) void*)g,
        (__attribute__((address_space(3))) void*)l, 16, 0, 0);
}

// ---------------------------------------------------------------------------
// Kernel 1: fp32 -> f16 conversion for the 4 weight matrices ONLY (4 MB).
// ---------------------------------------------------------------------------
#define CVT_W8 32768     // x8-groups per weight (512*512/8)

__global__ __launch_bounds__(256) void cvt_w(
    const float* __restrict__ wq, const float* __restrict__ wk,
    const float* __restrict__ wv, const float* __restrict__ wo,
    u16* __restrict__ ws)
{
    int i = blockIdx.x * 256 + threadIdx.x;   // 0 .. 131071
    int sel = i >> 15;
    int idx = i & 32767;
    const float* src = (sel == 0) ? wq : (sel == 1) ? wk : (sel == 2) ? wv : wo;
    u16* dst = ws + U_W + (size_t)sel * U_WSZ;
    fvec4 f0 = ((const fvec4*)src)[idx * 2];
    fvec4 f1 = ((const fvec4*)src)[idx * 2 + 1];
    u16x8 o;
    o[0] = f2h(f0[0]); o[1] = f2h(f0[1]); o[2] = f2h(f0[2]); o[3] = f2h(f0[3]);
    o[4] = f2h(f1[0]); o[5] = f2h(f1[1]); o[6] = f2h(f1[2]); o[7] = f2h(f1[3]);
    ((u16x8*)dst)[idx] = o;
}

// ---------------------------------------------------------------------------
// shared GEMM epilogue: C row = q4*4 + r (+tile), col = l15 (+tile)
// OUT: 0 = f32 row-major, 1 = f16 row-major, 2 = f16 transposed (V^T write).
// ---------------------------------------------------------------------------
template<int OUT>
__device__ __forceinline__ void gemm_epi(
    f32x4 (&acc)[4][4], const float* __restrict__ bias, float scale,
    void* __restrict__ Cout, int bm, int bn, int wm, int wn, int l15, int q4)
{
    #pragma unroll
    for (int mt = 0; mt < 4; ++mt) {
        #pragma unroll
        for (int nt = 0; nt < 4; ++nt) {
            int col = bn + wn + nt * 16 + l15;
            float bv = bias[col];
            int row0 = bm + wm + mt * 16 + q4 * 4;
            if (OUT == 2) {
                // V^T: Vt[b][d=col][s] ; rows r are 4 consecutive s -> u16x4
                u16x4 o;
                #pragma unroll
                for (int r = 0; r < 4; ++r)
                    o[r] = f2h((acc[mt][nt][r] + bv) * scale);
                *(u16x4*)((u16*)Cout + ((size_t)(row0 >> 11) * D_ + col) * S_ + (row0 & 2047)) = o;
            } else {
                #pragma unroll
                for (int r = 0; r < 4; ++r) {
                    float val = (acc[mt][nt][r] + bv) * scale;
                    if (OUT == 1)
                        ((u16*)Cout)[(size_t)(row0 + r) * D_ + col] = f2h(val);
                    else
                        ((float*)Cout)[(size_t)(row0 + r) * D_ + col] = val;
                }
            }
        }
    }
}

// ---------------------------------------------------------------------------
// GEMM variant A (QKV projections): A is fp32 (raw input), W is f16.
// BM=128, BN=128, BK=64; 4 waves 2x2, each wave 64x64 (acc[4][4]).
// Reg-staged pipeline (T14): stage regs->LDS, barrier, issue NEXT K-step's
// global loads, then compute. fp32->f16 conversion fused into staging.
// ---------------------------------------------------------------------------
template<int OUT>
__device__ __forceinline__ void gemm_body_f32A(
    const float* __restrict__ A, const u16* __restrict__ W,
    const float* __restrict__ bias, float scale, void* __restrict__ Cout)
{
    __shared__ u16 As[2][128 * 32];   // [dh][row][32]
    __shared__ u16 Bs[2][128 * 32];

    const int tid  = threadIdx.x;
    const int lane = tid & 63;
    const int w    = tid >> 6;
    const int l15  = lane & 15;
    const int q4   = lane >> 4;
    const int bm   = blockIdx.x * 128;
    const int bn   = blockIdx.y * 128;
    const int wm   = (w >> 1) * 64;   // wave row quadrant
    const int wn   = (w & 1) * 64;    // wave col quadrant

    // granule g = dh*2+p covers i = p*256+tid: row=i>>2, k-col = dh*32+(i&3)*8
    fvec4 ar[4][2];   // A prefetch (fp32)
    u16x8 wr[4];      // W prefetch (f16 passthrough)
    const float* Ab = A + (size_t)bm * K_;
    const u16*   Wb = W + (size_t)bn * K_;

    auto LOAD = [&](int kt) {
        #pragma unroll
        for (int g = 0; g < 4; ++g) {
            const int dh = g >> 1, p = g & 1;
            const int i = p * 256 + tid;
            const int row = i >> 2;
            const int col = kt + dh * 32 + (i & 3) * 8;
            ar[g][0] = *(const fvec4*)(Ab + (size_t)row * K_ + col);
            ar[g][1] = *(const fvec4*)(Ab + (size_t)row * K_ + col + 4);
            wr[g]    = *(const u16x8*)(Wb + (size_t)row * K_ + col);
        }
    };

    LOAD(0);
    f32x4 acc[4][4] = {};

    for (int kt = 0; kt < K_; kt += 64) {
        __syncthreads();   // previous compute done reading LDS
        #pragma unroll
        for (int g = 0; g < 4; ++g) {
            const int dh = g >> 1, p = g & 1;
            u16x8 o;
            #pragma unroll
            for (int e = 0; e < 4; ++e) {
                o[e]     = f2h(ar[g][0][e]);
                o[e + 4] = f2h(ar[g][1][e]);
            }
            *(u16x8*)(&As[dh][(p * 256 + tid) * 8]) = o;
            *(u16x8*)(&Bs[dh][(p * 256 + tid) * 8]) = wr[g];
        }
        __syncthreads();   // LDS visible
        if (kt + 64 < K_) LOAD(kt + 64);   // overlap with compute below

        #pragma unroll
        for (int dh = 0; dh < 2; ++dh) {
            f16x8 af[4], bf[4];
            #pragma unroll
            for (int mt = 0; mt < 4; ++mt)
                af[mt] = *(const f16x8*)(&As[dh][(wm + mt * 16 + l15) * 32 + q4 * 8]);
            #pragma unroll
            for (int nt = 0; nt < 4; ++nt)
                bf[nt] = *(const f16x8*)(&Bs[dh][(wn + nt * 16 + l15) * 32 + q4 * 8]);
            #pragma unroll
            for (int mt = 0; mt < 4; ++mt)
                #pragma unroll
                for (int nt = 0; nt < 4; ++nt)
                    acc[mt][nt] = __builtin_amdgcn_mfma_f32_16x16x32_f16(
                        af[mt], bf[nt], acc[mt][nt], 0, 0, 0);
        }
    }

    gemm_epi<OUT>(acc, bias, scale, Cout, bm, bn, wm, wn, l15, q4);
}

// ---------------------------------------------------------------------------
// GEMM variant B (output projection): A and W both f16, gld16 staging.
// ---------------------------------------------------------------------------
template<int OUT>
__device__ __forceinline__ void gemm_body(
    const u16* __restrict__ A, const u16* __restrict__ W,
    const float* __restrict__ bias, float scale, void* __restrict__ Cout)
{
    __shared__ u16 As[2][128 * 32];   // [dh][row][32]
    __shared__ u16 Bs[2][128 * 32];

    const int tid  = threadIdx.x;
    const int lane = tid & 63;
    const int w    = tid >> 6;
    const int l15  = lane & 15;
    const int q4   = lane >> 4;
    const int bm   = blockIdx.x * 128;
    const int bn   = blockIdx.y * 128;
    const int wm   = (w >> 1) * 64;
    const int wn   = (w & 1) * 64;

    f32x4 acc[4][4] = {};

    for (int kt = 0; kt < K_; kt += 64) {
        __syncthreads();
        #pragma unroll
        for (int dh = 0; dh < 2; ++dh)
            #pragma unroll
            for (int p = 0; p < 2; ++p) {
                int i = p * 256 + tid;
                gld16(A + (size_t)(bm + (i >> 2)) * K_ + kt + dh * 32 + (i & 3) * 8,
                      &As[dh][p * 2048 + w * 512]);
                gld16(W + (size_t)(bn + (i >> 2)) * K_ + kt + dh * 32 + (i & 3) * 8,
                      &Bs[dh][p * 2048 + w * 512]);
            }
        __syncthreads();

        #pragma unroll
        for (int dh = 0; dh < 2; ++dh) {
            f16x8 af[4], bf[4];
            #pragma unroll
            for (int mt = 0; mt < 4; ++mt)
                af[mt] = *(const f16x8*)(&As[dh][(wm + mt * 16 + l15) * 32 + q4 * 8]);
            #pragma unroll
            for (int nt = 0; nt < 4; ++nt)
                bf[nt] = *(const f16x8*)(&Bs[dh][(wn + nt * 16 + l15) * 32 + q4 * 8]);
            #pragma unroll
            for (int mt = 0; mt < 4; ++mt)
                #pragma unroll
                for (int nt = 0; nt < 4; ++nt)
                    acc[mt][nt] = __builtin_amdgcn_mfma_f32_16x16x32_f16(
                        af[mt], bf[nt], acc[mt][nt], 0, 0, 0);
        }
    }

    gemm_epi<OUT>(acc, bias, scale, Cout, bm, bn, wm, wn, l15, q4);
}

__global__ __launch_bounds__(256) void gemm_qkv(
    const float* __restrict__ q, const float* __restrict__ k, const float* __restrict__ v,
    const u16* __restrict__ Wbase,
    const float* __restrict__ b0, const float* __restrict__ b1,
    const float* __restrict__ b2, u16* __restrict__ ws)
{
    int z = blockIdx.z;
    if (z == 0)
        gemm_body_f32A<1>(q, Wbase, b0, QSCALE, ws + U_Q);
    else if (z == 1)
        gemm_body_f32A<1>(k, Wbase + U_WSZ, b1, 1.0f, ws + U_K);
    else
        gemm_body_f32A<2>(v, Wbase + 2 * U_WSZ, b2, 1.0f, ws + U_VT);
}

__global__ __launch_bounds__(256) void gemm_out_k(
    const u16* __restrict__ A, const u16* __restrict__ W,
    const float* __restrict__ bias, float* __restrict__ C)
{
    gemm_body<0>(A, W, bias, 1.0f, C);
}

// ---------------------------------------------------------------------------
// Kernel 3: flash attention — 512 threads / 8 waves, 128 q-rows per block.
// ROUND-7 CHANGE: pair-pipelined main loop. LDS holds TWO pairs of 64-key
// chunks (4 chunk-buffers, 73.7 KB). Per 128-key iteration: ONE barrier,
// then stage pair p^1 from regs (loaded last iteration), issue global
// prefetch for pair p^2, then compute BOTH chunks of pair p back-to-back.
// Barriers halve (32 -> 16) and each barrier interval holds 32 MFMA with
// two INDEPENDENT softmax chains — chunk B's QK^T MFMAs overlap chunk A's
// exp2/pack VALU stretch within one wave (T15 mechanism) on top of the
// cross-wave overlap. V additive swizzle from R6 (conflicts 9.4M -> 4.2M)
// retained unchanged.
// ---------------------------------------------------------------------------
__global__ __launch_bounds__(512) void flash_attn(
    const u16* __restrict__ Q, const u16* __restrict__ K,
    const u16* __restrict__ Vt, u16* __restrict__ Oa)
{
    __shared__ u16 smem[2][2][2][64 * 72];   // [pair][half][0=Ks,1=Vs][64x72]
    __shared__ float lred[2][128];

    const int tid  = threadIdx.x;
    const int lane = tid & 63;
    const int w    = tid >> 6;
    const int wq   = w >> 1;   // 0..3
    const int wk   = w & 1;
    const int l15  = lane & 15;
    const int q4   = lane >> 4;

    // XCD swizzle: 512 blocks, all 16 q-tiles of one (b,h) on one XCD
    const int n   = blockIdx.x;
    const int idx = n >> 3;
    const int bh  = (n & 7) * 4 + (idx >> 4);
    const int qt  = idx & 15;
    const int b = bh >> 3, h = bh & 7;
    const int qbase = qt * 128;

    // Q fragments (B-operand of 16x16x32): q = wq*32 + g*16 + l15
    f16x8 qf[2][2];
    #pragma unroll
    for (int g = 0; g < 2; ++g)
        #pragma unroll
        for (int dh = 0; dh < 2; ++dh)
            qf[g][dh] = *(const f16x8*)(Q + (size_t)(b * T_ + qbase + wq * 32 + g * 16 + l15) * D_
                                          + h * HD_ + dh * 32 + q4 * 8);

    // coalesced staging: 512 threads cover 64 rows x 64 cols in one pass
    const int r0 = tid >> 3;          // 0..63
    const int c0 = (tid & 7) * 8;     // 0..56
    // additive V swizzle: phys granule = (s4 + (row&7)) mod 16, 8B granules
    const int pA = ((2 * (tid & 7)) + (r0 & 7)) & 15;
    const int pB = ((2 * (tid & 7)) + 1 + (r0 & 7)) & 15;
    const u16* kp = K  + (size_t)(b * S_ + r0) * D_ + h * HD_ + c0;
    const u16* vp = Vt + (size_t)(b * D_ + h * HD_ + r0) * S_ + c0;

    u16x8 kr[2], vr[2];   // register prefetch for one PAIR (2 x 64-key chunks)

    auto LOADPAIR = [&]() {
        kr[0] = *(const u16x8*)kp;
        kr[1] = *(const u16x8*)(kp + (size_t)64 * D_);
        vr[0] = *(const u16x8*)vp;
        vr[1] = *(const u16x8*)(vp + 64);
        kp += (size_t)128 * D_;
        vp += 128;
    };

    auto STAGE = [&](int p) {
        #pragma unroll
        for (int hf = 0; hf < 2; ++hf) {
            u16* Ksb = &smem[p][hf][0][0];
            u16* Vsb = &smem[p][hf][1][0];
            *(u16x8*)(&Ksb[r0 * 72 + c0]) = kr[hf];
            u16x4 lo, hi;
            lo[0] = vr[hf][0]; lo[1] = vr[hf][1]; lo[2] = vr[hf][2]; lo[3] = vr[hf][3];
            hi[0] = vr[hf][4]; hi[1] = vr[hf][5]; hi[2] = vr[hf][6]; hi[3] = vr[hf][7];
            *(u16x4*)(&Vsb[r0 * 72 + pA * 4]) = lo;
            *(u16x4*)(&Vsb[r0 * 72 + pB * 4]) = hi;
        }
    };

    float l_part[2] = {0.f, 0.f};
    f32x4 acc[2][4] = {};   // O[q=wq*32+g*16+q4*4+r][d=nt*16+l15] (wk-partial)

    auto COMPUTE = [&](const u16* Ksb, const u16* Vsb) {
        // K quadrant A-fragments (keys wk*32 + t*16 + l15)
        f16x8 kf[2][2];
        #pragma unroll
        for (int t = 0; t < 2; ++t)
            #pragma unroll
            for (int dh = 0; dh < 2; ++dh)
                kf[t][dh] = *(const f16x8*)(&Ksb[(wk * 32 + t * 16 + l15) * 72 + dh * 32 + q4 * 8]);

        // S^T quadrant + softmax numerator; pack P A-frag with key order
        // kappa(q4, j) = wk*32 + (j>>2)*16 + q4*4 + (j&3)
        f16x8 pf8[2];
        #pragma unroll
        for (int t = 0; t < 2; ++t) {
            #pragma unroll
            for (int g = 0; g < 2; ++g) {
                f32x4 sacc = {};
                sacc = __builtin_amdgcn_mfma_f32_16x16x32_f16(kf[t][0], qf[g][0], sacc, 0, 0, 0);
                sacc = __builtin_amdgcn_mfma_f32_16x16x32_f16(kf[t][1], qf[g][1], sacc, 0, 0, 0);
                #pragma unroll
                for (int r = 0; r < 4; ++r) {
                    float p = __builtin_amdgcn_exp2f(sacc[r]);
                    l_part[g] += p;
                    pf8[g][t * 4 + r] = (_Float16)p;
                }
            }
        }

        // O += P x V, one x32 MFMA per nt (B-frag in same permuted key order)
        #pragma unroll
        for (int nt = 0; nt < 4; ++nt) {
            const int drow = (nt * 16 + l15) * 72;
            const int a8 = l15 & 7;
            f16x4 v0 = *(const f16x4*)(&Vsb[drow + (((wk * 8 + 0 + q4 + a8) & 15) * 4)]);
            f16x4 v1 = *(const f16x4*)(&Vsb[drow + (((wk * 8 + 4 + q4 + a8) & 15) * 4)]);
            f16x8 v8;
            v8[0] = v0[0]; v8[1] = v0[1]; v8[2] = v0[2]; v8[3] = v0[3];
            v8[4] = v1[0]; v8[5] = v1[1]; v8[6] = v1[2]; v8[7] = v1[3];
            #pragma unroll
            for (int g = 0; g < 2; ++g)
                acc[g][nt] = __builtin_amdgcn_mfma_f32_16x16x32_f16(pf8[g], v8, acc[g][nt], 0, 0, 0);
        }
    };

    // prologue: stage pair 0, start loads for pair 1
    LOADPAIR();      // regs <- chunks {0, 64}
    STAGE(0);
    LOADPAIR();      // regs <- chunks {128, 192} (in flight during first compute)

    for (int sc = 0; sc < S_; sc += 128) {
        const int p = (sc >> 7) & 1;
        __syncthreads();   // pair p staged & visible; prior compute on p^1 done
        if (sc + 128 < S_) {
            STAGE(p ^ 1);                     // regs from last LOADPAIR
            if (sc + 256 < S_) LOADPAIR();    // refill regs; lands during compute
        }
        __builtin_amdgcn_s_setprio(1);
        COMPUTE(&smem[p][0][0][0], &smem[p][0][1][0]);
        COMPUTE(&smem[p][1][0][0], &smem[p][1][1][0]);
        __builtin_amdgcn_s_setprio(0);
    }

    // ---- epilogue: 2-way cross-wave (wk) reduction of partial O and l ----
    #pragma unroll
    for (int g = 0; g < 2; ++g) {
        l_part[g] += __shfl_xor(l_part[g], 16);
        l_part[g] += __shfl_xor(l_part[g], 32);
    }
    if (q4 == 0) {
        #pragma unroll
        for (int g = 0; g < 2; ++g) lred[wk][wq * 32 + g * 16 + l15] = l_part[g];
    }
    __syncthreads();   // lred visible AND all smem reads done (Obuf aliases smem)

    float* Obuf = (float*)smem;   // 128q x 64d fp32, col groups swizzled by ^q4
    if (wk == 1) {
        #pragma unroll
        for (int g = 0; g < 2; ++g)
            #pragma unroll
            for (int nt = 0; nt < 4; ++nt)
                #pragma unroll
                for (int r = 0; r < 4; ++r)
                    Obuf[(wq * 32 + g * 16 + q4 * 4 + r) * 64 + ((nt ^ q4) & 3) * 16 + l15] = acc[g][nt][r];
    }
    __syncthreads();
    if (wk == 0) {
        float inv[2][4];
        #pragma unroll
        for (int g = 0; g < 2; ++g)
            #pragma unroll
            for (int r = 0; r < 4; ++r) {
                int qq = wq * 32 + g * 16 + q4 * 4 + r;
                inv[g][r] = 1.0f / (lred[0][qq] + lred[1][qq]);
            }
        #pragma unroll
        for (int g = 0; g < 2; ++g)
            #pragma unroll
            for (int nt = 0; nt < 4; ++nt)
                #pragma unroll
                for (int r = 0; r < 4; ++r) {
                    float val = (Obuf[(wq * 32 + g * 16 + q4 * 4 + r) * 64 + ((nt ^ q4) & 3) * 16 + l15]
                                 + acc[g][nt][r]) * inv[g][r];
                    Oa[(size_t)(b * T_ + qbase + wq * 32 + g * 16 + q4 * 4 + r) * D_
                       + h * HD_ + nt * 16 + l15] = f2h(val);
                }
    }
}

// ---------------------------------------------------------------------------
extern "C" void kernel_launch(void* const* d_in, const int* in_sizes, int n_in,
                              void* d_out, int out_size, void* d_ws, size_t ws_size,
                              hipStream_t stream)
{
    (void)in_sizes; (void)n_in; (void)out_size; (void)ws_size;
    const float* q  = (const float*)d_in[0];
    const float* k  = (const float*)d_in[1];
    const float* v  = (const float*)d_in[2];
    const float* Wq = (const float*)d_in[3];
    const float* bq = (const float*)d_in[4];
    const float* Wk = (const float*)d_in[5];
    const float* bk = (const float*)d_in[6];
    const float* Wv = (const float*)d_in[7];
    const float* bv = (const float*)d_in[8];
    const float* Wo = (const float*)d_in[9];
    const float* bo = (const float*)d_in[10];

    u16* ws  = (u16*)d_ws;
    u16* WBF = ws + U_W;
    u16* Qp  = ws + U_Q;
    u16* Kp  = ws + U_K;
    u16* VTp = ws + U_VT;
    u16* AO  = ws + U_QBF;
    u16* WOp = WBF + 3 * U_WSZ;

    cvt_w<<<512, 256, 0, stream>>>(Wq, Wk, Wv, Wo, ws);
    gemm_qkv<<<dim3(M_ / 128, D_ / 128, 3), 256, 0, stream>>>(q, k, v, WBF, bq, bk, bv, ws);
    flash_attn<<<dim3(512), 512, 0, stream>>>(Qp, Kp, VTp, AO);
    gemm_out_k<<<dim3(M_ / 128, D_ / 128), 256, 0, stream>>>(AO, WOp, bo, (float*)d_out);
}

// Round 9
// 182.516 us; speedup vs baseline: 1.0388x; 1.0388x over previous
//
#include <hip/hip_runtime.h>
#include <stdint.h>

typedef unsigned short u16;
typedef u16  u16x4 __attribute__((ext_vector_type(4)));
typedef u16  u16x8 __attribute__((ext_vector_type(8)));
typedef _Float16 f16x4 __attribute__((ext_vector_type(4)));
typedef _Float16 f16x8 __attribute__((ext_vector_type(8)));
typedef float f32x4 __attribute__((ext_vector_type(4)));
typedef float fvec4 __attribute__((ext_vector_type(4)));

#define B_ 4
#define T_ 2048
#define S_ 2048
#define D_ 512
#define H_ 8
#define HD_ 64
#define M_ 8192   // B*T == B*S
#define K_ 512    // projection inner dim

// workspace offsets in u16 (f16) element units
#define U_QBF  0u          // (free) reused as attn_out
#define U_Q    12582912u   // projected Q f16 (pre-scaled by log2e/8)
#define U_K    16777216u   // projected K f16
#define U_VT   20971520u   // projected V^T f16 (B, D, S) — written by gemm_qkv z=2
#define U_W    25165824u   // Wq,Wk,Wv,Wo f16 (262144 u16 each)
#define U_WSZ  262144u

#define QSCALE 0.1803368801111244f   // log2(e) / sqrt(HD), folded into Q projection

__device__ __forceinline__ u16 f2h(float f) {
    union { _Float16 h; u16 u; } c;
    c.h = (_Float16)f;
    return c.u;
}

// async global->LDS 16B copy: LDS dest = wave-uniform base + lane*16.
// ONLY valid when fragment order is ALSO global-contiguous.
__device__ __forceinline__ void gld16(const u16* g, u16* l) {
    __builtin_amdgcn_global_load_lds(
        (const __attribute__((address_space(1))) void*)g,
        (__attribute__((address_space(3))) void*)l, 16, 0, 0);
}

// ---------------------------------------------------------------------------
// Kernel 1: fp32 -> f16 conversion for the 4 weight matrices ONLY (4 MB).
// ---------------------------------------------------------------------------
#define CVT_W8 32768     // x8-groups per weight (512*512/8)

__global__ __launch_bounds__(256) void cvt_w(
    const float* __restrict__ wq, const float* __restrict__ wk,
    const float* __restrict__ wv, const float* __restrict__ wo,
    u16* __restrict__ ws)
{
    int i = blockIdx.x * 256 + threadIdx.x;   // 0 .. 131071
    int sel = i >> 15;
    int idx = i & 32767;
    const float* src = (sel == 0) ? wq : (sel == 1) ? wk : (sel == 2) ? wv : wo;
    u16* dst = ws + U_W + (size_t)sel * U_WSZ;
    fvec4 f0 = ((const fvec4*)src)[idx * 2];
    fvec4 f1 = ((const fvec4*)src)[idx * 2 + 1];
    u16x8 o;
    o[0] = f2h(f0[0]); o[1] = f2h(f0[1]); o[2] = f2h(f0[2]); o[3] = f2h(f0[3]);
    o[4] = f2h(f1[0]); o[5] = f2h(f1[1]); o[6] = f2h(f1[2]); o[7] = f2h(f1[3]);
    ((u16x8*)dst)[idx] = o;
}

// ---------------------------------------------------------------------------
// shared GEMM epilogue: C row = q4*4 + r (+tile), col = l15 (+tile)
// OUT: 0 = f32 row-major, 1 = f16 row-major, 2 = f16 transposed (V^T write).
// ---------------------------------------------------------------------------
template<int OUT>
__device__ __forceinline__ void gemm_epi(
    f32x4 (&acc)[4][4], const float* __restrict__ bias, float scale,
    void* __restrict__ Cout, int bm, int bn, int wm, int wn, int l15, int q4)
{
    #pragma unroll
    for (int mt = 0; mt < 4; ++mt) {
        #pragma unroll
        for (int nt = 0; nt < 4; ++nt) {
            int col = bn + wn + nt * 16 + l15;
            float bv = bias[col];
            int row0 = bm + wm + mt * 16 + q4 * 4;
            if (OUT == 2) {
                // V^T: Vt[b][d=col][s] ; rows r are 4 consecutive s -> u16x4
                u16x4 o;
                #pragma unroll
                for (int r = 0; r < 4; ++r)
                    o[r] = f2h((acc[mt][nt][r] + bv) * scale);
                *(u16x4*)((u16*)Cout + ((size_t)(row0 >> 11) * D_ + col) * S_ + (row0 & 2047)) = o;
            } else {
                #pragma unroll
                for (int r = 0; r < 4; ++r) {
                    float val = (acc[mt][nt][r] + bv) * scale;
                    if (OUT == 1)
                        ((u16*)Cout)[(size_t)(row0 + r) * D_ + col] = f2h(val);
                    else
                        ((float*)Cout)[(size_t)(row0 + r) * D_ + col] = val;
                }
            }
        }
    }
}

// ---------------------------------------------------------------------------
// GEMM variant A (QKV projections): A is fp32 (raw input), W is f16.
// BM=128, BN=128, BK=64; 4 waves 2x2, each wave 64x64 (acc[4][4]).
// Reg-staged pipeline (T14): stage regs->LDS, barrier, issue NEXT K-step's
// global loads, then compute. fp32->f16 conversion fused into staging.
// ---------------------------------------------------------------------------
template<int OUT>
__device__ __forceinline__ void gemm_body_f32A(
    const float* __restrict__ A, const u16* __restrict__ W,
    const float* __restrict__ bias, float scale, void* __restrict__ Cout)
{
    __shared__ u16 As[2][128 * 32];   // [dh][row][32]
    __shared__ u16 Bs[2][128 * 32];

    const int tid  = threadIdx.x;
    const int lane = tid & 63;
    const int w    = tid >> 6;
    const int l15  = lane & 15;
    const int q4   = lane >> 4;
    const int bm   = blockIdx.x * 128;
    const int bn   = blockIdx.y * 128;
    const int wm   = (w >> 1) * 64;   // wave row quadrant
    const int wn   = (w & 1) * 64;    // wave col quadrant

    // granule g = dh*2+p covers i = p*256+tid: row=i>>2, k-col = dh*32+(i&3)*8
    fvec4 ar[4][2];   // A prefetch (fp32)
    u16x8 wr[4];      // W prefetch (f16 passthrough)
    const float* Ab = A + (size_t)bm * K_;
    const u16*   Wb = W + (size_t)bn * K_;

    auto LOAD = [&](int kt) {
        #pragma unroll
        for (int g = 0; g < 4; ++g) {
            const int dh = g >> 1, p = g & 1;
            const int i = p * 256 + tid;
            const int row = i >> 2;
            const int col = kt + dh * 32 + (i & 3) * 8;
            ar[g][0] = *(const fvec4*)(Ab + (size_t)row * K_ + col);
            ar[g][1] = *(const fvec4*)(Ab + (size_t)row * K_ + col + 4);
            wr[g]    = *(const u16x8*)(Wb + (size_t)row * K_ + col);
        }
    };

    LOAD(0);
    f32x4 acc[4][4] = {};

    for (int kt = 0; kt < K_; kt += 64) {
        __syncthreads();   // previous compute done reading LDS
        #pragma unroll
        for (int g = 0; g < 4; ++g) {
            const int dh = g >> 1, p = g & 1;
            u16x8 o;
            #pragma unroll
            for (int e = 0; e < 4; ++e) {
                o[e]     = f2h(ar[g][0][e]);
                o[e + 4] = f2h(ar[g][1][e]);
            }
            *(u16x8*)(&As[dh][(p * 256 + tid) * 8]) = o;
            *(u16x8*)(&Bs[dh][(p * 256 + tid) * 8]) = wr[g];
        }
        __syncthreads();   // LDS visible
        if (kt + 64 < K_) LOAD(kt + 64);   // overlap with compute below

        #pragma unroll
        for (int dh = 0; dh < 2; ++dh) {
            f16x8 af[4], bf[4];
            #pragma unroll
            for (int mt = 0; mt < 4; ++mt)
                af[mt] = *(const f16x8*)(&As[dh][(wm + mt * 16 + l15) * 32 + q4 * 8]);
            #pragma unroll
            for (int nt = 0; nt < 4; ++nt)
                bf[nt] = *(const f16x8*)(&Bs[dh][(wn + nt * 16 + l15) * 32 + q4 * 8]);
            #pragma unroll
            for (int mt = 0; mt < 4; ++mt)
                #pragma unroll
                for (int nt = 0; nt < 4; ++nt)
                    acc[mt][nt] = __builtin_amdgcn_mfma_f32_16x16x32_f16(
                        af[mt], bf[nt], acc[mt][nt], 0, 0, 0);
        }
    }

    gemm_epi<OUT>(acc, bias, scale, Cout, bm, bn, wm, wn, l15, q4);
}

// ---------------------------------------------------------------------------
// GEMM variant B (output projection): A and W both f16, gld16 staging.
// ---------------------------------------------------------------------------
template<int OUT>
__device__ __forceinline__ void gemm_body(
    const u16* __restrict__ A, const u16* __restrict__ W,
    const float* __restrict__ bias, float scale, void* __restrict__ Cout)
{
    __shared__ u16 As[2][128 * 32];   // [dh][row][32]
    __shared__ u16 Bs[2][128 * 32];

    const int tid  = threadIdx.x;
    const int lane = tid & 63;
    const int w    = tid >> 6;
    const int l15  = lane & 15;
    const int q4   = lane >> 4;
    const int bm   = blockIdx.x * 128;
    const int bn   = blockIdx.y * 128;
    const int wm   = (w >> 1) * 64;
    const int wn   = (w & 1) * 64;

    f32x4 acc[4][4] = {};

    for (int kt = 0; kt < K_; kt += 64) {
        __syncthreads();
        #pragma unroll
        for (int dh = 0; dh < 2; ++dh)
            #pragma unroll
            for (int p = 0; p < 2; ++p) {
                int i = p * 256 + tid;
                gld16(A + (size_t)(bm + (i >> 2)) * K_ + kt + dh * 32 + (i & 3) * 8,
                      &As[dh][p * 2048 + w * 512]);
                gld16(W + (size_t)(bn + (i >> 2)) * K_ + kt + dh * 32 + (i & 3) * 8,
                      &Bs[dh][p * 2048 + w * 512]);
            }
        __syncthreads();

        #pragma unroll
        for (int dh = 0; dh < 2; ++dh) {
            f16x8 af[4], bf[4];
            #pragma unroll
            for (int mt = 0; mt < 4; ++mt)
                af[mt] = *(const f16x8*)(&As[dh][(wm + mt * 16 + l15) * 32 + q4 * 8]);
            #pragma unroll
            for (int nt = 0; nt < 4; ++nt)
                bf[nt] = *(const f16x8*)(&Bs[dh][(wn + nt * 16 + l15) * 32 + q4 * 8]);
            #pragma unroll
            for (int mt = 0; mt < 4; ++mt)
                #pragma unroll
                for (int nt = 0; nt < 4; ++nt)
                    acc[mt][nt] = __builtin_amdgcn_mfma_f32_16x16x32_f16(
                        af[mt], bf[nt], acc[mt][nt], 0, 0, 0);
        }
    }

    gemm_epi<OUT>(acc, bias, scale, Cout, bm, bn, wm, wn, l15, q4);
}

__global__ __launch_bounds__(256) void gemm_qkv(
    const float* __restrict__ q, const float* __restrict__ k, const float* __restrict__ v,
    const u16* __restrict__ Wbase,
    const float* __restrict__ b0, const float* __restrict__ b1,
    const float* __restrict__ b2, u16* __restrict__ ws)
{
    int z = blockIdx.z;
    if (z == 0)
        gemm_body_f32A<1>(q, Wbase, b0, QSCALE, ws + U_Q);
    else if (z == 1)
        gemm_body_f32A<1>(k, Wbase + U_WSZ, b1, 1.0f, ws + U_K);
    else
        gemm_body_f32A<2>(v, Wbase + 2 * U_WSZ, b2, 1.0f, ws + U_VT);
}

__global__ __launch_bounds__(256) void gemm_out_k(
    const u16* __restrict__ A, const u16* __restrict__ W,
    const float* __restrict__ bias, float* __restrict__ C)
{
    gemm_body<0>(A, W, bias, 1.0f, C);
}

// ---------------------------------------------------------------------------
// Kernel 3: flash attention — 512 threads / 8 waves, 128 q-rows per block.
// R6 structure REVERTED (R7's pair-pipeline halved blocks/CU capacity via
// 74.8KB LDS -> occupancy 32.5->18.6%, dur 43->50; barrier count < occupancy).
// ROUND-8 CHANGE (VALU trim, structure untouched):
//  (a) v8 assembled via subvector union writes, not 8 element movs (~32
//      v_mov/chunk removed).
//  (b) softmax denominator l computed on the MFMA pipe: acc_l[g] =
//      mfma(pf8[g], ones) — k=32 sums the wave's whole 32-key half. Removes
//      16 serial VALU adds/chunk AND the epilogue shuffle reduce; l is now
//      the exact sum of the f16-rounded P used in PV (more self-consistent).
//      Cost: +2 MFMA/chunk on a 32%-busy pipe.
// ---------------------------------------------------------------------------
__global__ __launch_bounds__(512) void flash_attn(
    const u16* __restrict__ Q, const u16* __restrict__ K,
    const u16* __restrict__ Vt, u16* __restrict__ Oa)
{
    __shared__ u16 smem[2][2][64 * 72];   // [buf][0]=Ks [key][d], [buf][1]=Vs [d][s-swz]
    __shared__ float lred[2][128];

    const int tid  = threadIdx.x;
    const int lane = tid & 63;
    const int w    = tid >> 6;
    const int wq   = w >> 1;   // 0..3
    const int wk   = w & 1;
    const int l15  = lane & 15;
    const int q4   = lane >> 4;

    // XCD swizzle: 512 blocks, all 16 q-tiles of one (b,h) on one XCD
    const int n   = blockIdx.x;
    const int idx = n >> 3;
    const int bh  = (n & 7) * 4 + (idx >> 4);
    const int qt  = idx & 15;
    const int b = bh >> 3, h = bh & 7;
    const int qbase = qt * 128;

    // Q fragments (B-operand of 16x16x32): q = wq*32 + g*16 + l15
    f16x8 qf[2][2];
    #pragma unroll
    for (int g = 0; g < 2; ++g)
        #pragma unroll
        for (int dh = 0; dh < 2; ++dh)
            qf[g][dh] = *(const f16x8*)(Q + (size_t)(b * T_ + qbase + wq * 32 + g * 16 + l15) * D_
                                          + h * HD_ + dh * 32 + q4 * 8);

    // ones B-operand for the l-MFMA (k=32 row-sum of P)
    f16x8 ones8;
    #pragma unroll
    for (int e = 0; e < 8; ++e) ones8[e] = (_Float16)1.0f;

    // coalesced staging: 512 threads cover 64 rows x 64 cols in one pass
    const int r0 = tid >> 3;          // 0..63
    const int c0 = (tid & 7) * 8;     // 0..56
    // additive V swizzle: phys granule = (s4 + (row&7)) mod 16, 8B granules
    const int pA = ((2 * (tid & 7)) + (r0 & 7)) & 15;
    const int pB = ((2 * (tid & 7)) + 1 + (r0 & 7)) & 15;
    const u16* kp = K  + (size_t)(b * S_ + r0) * D_ + h * HD_ + c0;
    const u16* vp = Vt + (size_t)(b * D_ + h * HD_ + r0) * S_ + c0;

    // prefetch chunk 0
    u16x8 kr = *(const u16x8*)kp;
    u16x8 vr = *(const u16x8*)vp;
    kp += (size_t)64 * D_;
    vp += 64;

    f32x4 acc_l[2] = {};    // l(q) replicated across cols; row = q4*4+r (+g*16)
    f32x4 acc[2][4] = {};   // O[q=wq*32+g*16+q4*4+r][d=nt*16+l15] (wk-partial)

    for (int sc = 0; sc < S_; sc += 128) {
        #pragma unroll
        for (int hf = 0; hf < 2; ++hf) {
            u16* Ksb = &smem[hf][0][0];
            u16* Vsb = &smem[hf][1][0];
            // stage prefetched chunk into buf[hf]
            *(u16x8*)(&Ksb[r0 * 72 + c0]) = kr;
            {
                u16x4 lo, hi;
                lo[0] = vr[0]; lo[1] = vr[1]; lo[2] = vr[2]; lo[3] = vr[3];
                hi[0] = vr[4]; hi[1] = vr[5]; hi[2] = vr[6]; hi[3] = vr[7];
                *(u16x4*)(&Vsb[r0 * 72 + pA * 4]) = lo;
                *(u16x4*)(&Vsb[r0 * 72 + pB * 4]) = hi;
            }
            __syncthreads();
            // issue next chunk's global loads AFTER the barrier so the
            // barrier's vmcnt drain never waits on them; they land during
            // this chunk's compute.
            if (sc + hf * 64 + 64 < S_) {
                kr = *(const u16x8*)kp;
                vr = *(const u16x8*)vp;
                kp += (size_t)64 * D_;
                vp += 64;
            }

            __builtin_amdgcn_s_setprio(1);
            // K quadrant A-fragments (keys wk*32 + t*16 + l15)
            f16x8 kf[2][2];
            #pragma unroll
            for (int t = 0; t < 2; ++t)
                #pragma unroll
                for (int dh = 0; dh < 2; ++dh)
                    kf[t][dh] = *(const f16x8*)(&Ksb[(wk * 32 + t * 16 + l15) * 72 + dh * 32 + q4 * 8]);

            // S^T quadrant + softmax numerator; pack P A-frag with key order
            // kappa(q4, j) = wk*32 + (j>>2)*16 + q4*4 + (j&3)
            f16x8 pf8[2];
            #pragma unroll
            for (int t = 0; t < 2; ++t) {
                #pragma unroll
                for (int g = 0; g < 2; ++g) {
                    f32x4 sacc = {};
                    sacc = __builtin_amdgcn_mfma_f32_16x16x32_f16(kf[t][0], qf[g][0], sacc, 0, 0, 0);
                    sacc = __builtin_amdgcn_mfma_f32_16x16x32_f16(kf[t][1], qf[g][1], sacc, 0, 0, 0);
                    #pragma unroll
                    for (int r = 0; r < 4; ++r)
                        pf8[g][t * 4 + r] = (_Float16)__builtin_amdgcn_exp2f(sacc[r]);
                }
            }

            // l(q) += P x ones on the MFMA pipe (sums this wave's 32 keys)
            #pragma unroll
            for (int g = 0; g < 2; ++g)
                acc_l[g] = __builtin_amdgcn_mfma_f32_16x16x32_f16(pf8[g], ones8, acc_l[g], 0, 0, 0);

            // O += P x V, one x32 MFMA per nt (B-frag in same permuted key order)
            #pragma unroll
            for (int nt = 0; nt < 4; ++nt) {
                const int drow = (nt * 16 + l15) * 72;
                const int a8 = l15 & 7;
                union { f16x8 v; f16x4 h[2]; } u;
                u.h[0] = *(const f16x4*)(&Vsb[drow + (((wk * 8 + 0 + q4 + a8) & 15) * 4)]);
                u.h[1] = *(const f16x4*)(&Vsb[drow + (((wk * 8 + 4 + q4 + a8) & 15) * 4)]);
                #pragma unroll
                for (int g = 0; g < 2; ++g)
                    acc[g][nt] = __builtin_amdgcn_mfma_f32_16x16x32_f16(pf8[g], u.v, acc[g][nt], 0, 0, 0);
            }
            __builtin_amdgcn_s_setprio(0);
        }
    }

    // ---- epilogue: 2-way cross-wave (wk) reduction of partial O and l ----
    // acc_l rows carry l(q) for q = wq*32 + g*16 + q4*4 + r (same value in
    // every col); one col-0 lane per q4 group writes it out.
    if (l15 == 0) {
        #pragma unroll
        for (int g = 0; g < 2; ++g)
            #pragma unroll
            for (int r = 0; r < 4; ++r)
                lred[wk][wq * 32 + g * 16 + q4 * 4 + r] = acc_l[g][r];
    }
    __syncthreads();   // lred visible AND all smem reads done (Obuf aliases smem)

    float* Obuf = (float*)smem;   // 128q x 64d fp32, col groups swizzled by ^q4
    if (wk == 1) {
        #pragma unroll
        for (int g = 0; g < 2; ++g)
            #pragma unroll
            for (int nt = 0; nt < 4; ++nt)
                #pragma unroll
                for (int r = 0; r < 4; ++r)
                    Obuf[(wq * 32 + g * 16 + q4 * 4 + r) * 64 + ((nt ^ q4) & 3) * 16 + l15] = acc[g][nt][r];
    }
    __syncthreads();
    if (wk == 0) {
        float inv[2][4];
        #pragma unroll
        for (int g = 0; g < 2; ++g)
            #pragma unroll
            for (int r = 0; r < 4; ++r) {
                int qq = wq * 32 + g * 16 + q4 * 4 + r;
                inv[g][r] = 1.0f / (lred[0][qq] + lred[1][qq]);
            }
        #pragma unroll
        for (int g = 0; g < 2; ++g)
            #pragma unroll
            for (int nt = 0; nt < 4; ++nt)
                #pragma unroll
                for (int r = 0; r < 4; ++r) {
                    float val = (Obuf[(wq * 32 + g * 16 + q4 * 4 + r) * 64 + ((nt ^ q4) & 3) * 16 + l15]
                                 + acc[g][nt][r]) * inv[g][r];
                    Oa[(size_t)(b * T_ + qbase + wq * 32 + g * 16 + q4 * 4 + r) * D_
                       + h * HD_ + nt * 16 + l15] = f2h(val);
                }
    }
}

// ---------------------------------------------------------------------------
extern "C" void kernel_launch(void* const* d_in, const int* in_sizes, int n_in,
                              void* d_out, int out_size, void* d_ws, size_t ws_size,
                              hipStream_t stream)
{
    (void)in_sizes; (void)n_in; (void)out_size; (void)ws_size;
    const float* q  = (const float*)d_in[0];
    const float* k  = (const float*)d_in[1];
    const float* v  = (const float*)d_in[2];
    const float* Wq = (const float*)d_in[3];
    const float* bq = (const float*)d_in[4];
    const float* Wk = (const float*)d_in[5];
    const float* bk = (const float*)d_in[6];
    const float* Wv = (const float*)d_in[7];
    const float* bv = (const float*)d_in[8];
    const float* Wo = (const float*)d_in[9];
    const float* bo = (const float*)d_in[10];

    u16* ws  = (u16*)d_ws;
    u16* WBF = ws + U_W;
    u16* Qp  = ws + U_Q;
    u16* Kp  = ws + U_K;
    u16* VTp = ws + U_VT;
    u16* AO  = ws + U_QBF;
    u16* WOp = WBF + 3 * U_WSZ;

    cvt_w<<<512, 256, 0, stream>>>(Wq, Wk, Wv, Wo, ws);
    gemm_qkv<<<dim3(M_ / 128, D_ / 128, 3), 256, 0, stream>>>(q, k, v, WBF, bq, bk, bv, ws);
    flash_attn<<<dim3(512), 512, 0, stream>>>(Qp, Kp, VTp, AO);
    gemm_out_k<<<dim3(M_ / 128, D_ / 128), 256, 0, stream>>>(AO, WOp, bo, (float*)d_out);
}